// Round 1
// baseline (702.550 us; speedup 1.0000x reference)
//
#include <hip/hip_runtime.h>
#include <hip/hip_bf16.h>

#define NN   4096
#define DIMM 256
#define HH   8
#define HC   2048   // H * C
#define CAP  128    // max in-degree capacity (binomial(4096,0.01) max ~75)

// ---------------------------------------------------------------------------
// Edge extraction: adj[j*N + i] != 0  =>  edge j -> i (source_to_target).
// Coalesced row-major scan, atomic append to per-target list.
// ---------------------------------------------------------------------------
__global__ __launch_bounds__(256) void build_edges_kernel(
    const float* __restrict__ adj, int* __restrict__ deg, int* __restrict__ nbr) {
  const int stride = gridDim.x * blockDim.x;
  for (int e = blockIdx.x * blockDim.x + threadIdx.x; e < NN * NN; e += stride) {
    if (adj[e] != 0.0f) {
      const int j = e >> 12;         // source row
      const int i = e & (NN - 1);    // target col
      const int slot = atomicAdd(&deg[i], 1);
      if (slot < CAP) nbr[i * CAP + slot] = j;
    }
  }
}

// ---------------------------------------------------------------------------
// f32 GEMM + bias: C[M x Nn] = A[M x K] @ B[K x Nn] + bias
// 64x64 block tile, 256 threads, 4x4 register tile, K-tile 16.
// ---------------------------------------------------------------------------
__global__ __launch_bounds__(256) void gemm_bias_kernel(
    const float* __restrict__ A, const float* __restrict__ B,
    const float* __restrict__ bias, float* __restrict__ C,
    int M, int Nn, int K) {
  __shared__ float As[16][64];
  __shared__ float Bs[16][64];
  const int t = threadIdx.x;
  const int tx = t & 15, ty = t >> 4;
  const int row0 = blockIdx.y * 64, col0 = blockIdx.x * 64;
  const int ra = t >> 2, ca = (t & 3) << 2;    // A-tile load coords
  const int rb = t >> 4, cb = (t & 15) << 2;   // B-tile load coords

  float acc[4][4] = {{0.f, 0.f, 0.f, 0.f}, {0.f, 0.f, 0.f, 0.f},
                     {0.f, 0.f, 0.f, 0.f}, {0.f, 0.f, 0.f, 0.f}};

  for (int kt = 0; kt < K; kt += 16) {
    const float4 av = *(const float4*)&A[(size_t)(row0 + ra) * K + kt + ca];
    const float4 bv = *(const float4*)&B[(size_t)(kt + rb) * Nn + col0 + cb];
    As[ca + 0][ra] = av.x;
    As[ca + 1][ra] = av.y;
    As[ca + 2][ra] = av.z;
    As[ca + 3][ra] = av.w;
    *(float4*)&Bs[rb][cb] = bv;
    __syncthreads();
#pragma unroll
    for (int kk = 0; kk < 16; ++kk) {
      const float4 a4 = *(const float4*)&As[kk][ty << 2];
      const float4 b4 = *(const float4*)&Bs[kk][tx << 2];
      const float aa[4] = {a4.x, a4.y, a4.z, a4.w};
      const float bb[4] = {b4.x, b4.y, b4.z, b4.w};
#pragma unroll
      for (int ii = 0; ii < 4; ++ii)
#pragma unroll
        for (int jj = 0; jj < 4; ++jj)
          acc[ii][jj] = fmaf(aa[ii], bb[jj], acc[ii][jj]);
    }
    __syncthreads();
  }

  const float4 bvec = *(const float4*)&bias[col0 + (tx << 2)];
#pragma unroll
  for (int ii = 0; ii < 4; ++ii) {
    float4 o;
    o.x = acc[ii][0] + bvec.x;
    o.y = acc[ii][1] + bvec.y;
    o.z = acc[ii][2] + bvec.z;
    o.w = acc[ii][3] + bvec.w;
    *(float4*)&C[(size_t)(row0 + (ty << 2) + ii) * Nn + col0 + (tx << 2)] = o;
  }
}

// ---------------------------------------------------------------------------
// Sparse attention + head-mean + skip + LayerNorm + residual.
// One block (256 threads = 4 waves) per target node i.
// ---------------------------------------------------------------------------
__global__ __launch_bounds__(256) void attn_ln_kernel(
    const float* __restrict__ q, const float* __restrict__ k,
    const float* __restrict__ v, const float* __restrict__ skip,
    const float* __restrict__ x, const int* __restrict__ deg,
    int* __restrict__ nbr, const float* __restrict__ gamma,
    const float* __restrict__ beta, float* __restrict__ out) {
  const int i = blockIdx.x;
  const int t = threadIdx.x;
  const int lane = t & 63, wave = t >> 6;

  __shared__ float qs[HC];
  __shared__ float sc[CAP * HH];
  __shared__ float mred[HH], lred[HH];
  __shared__ float w1[4], w2[4];

  // load q row (2048 f32) into LDS
  const float4* qrow = (const float4*)&q[(size_t)i * HC];
  float4* qs4 = (float4*)qs;
  qs4[t] = qrow[t];
  qs4[t + 256] = qrow[t + 256];

  int d = deg[i];
  if (d > CAP) d = CAP;

  // insertion-sort neighbor list (deterministic summation order; d ~ 41)
  if (t == 0 && d > 1) {
    int* lst = &nbr[i * CAP];
    for (int a = 1; a < d; ++a) {
      const int key = lst[a];
      int b2 = a - 1;
      while (b2 >= 0 && lst[b2] > key) { lst[b2 + 1] = lst[b2]; --b2; }
      lst[b2 + 1] = key;
    }
  }
  __syncthreads();

  // scores: wave w handles neighbors w, w+4, ...; per head: 64-lane dot of 256
  for (int n = wave; n < d; n += 4) {
    const int j = nbr[i * CAP + n];
    const float* krow = &k[(size_t)j * HC];
#pragma unroll
    for (int h = 0; h < HH; ++h) {
      const float4 kv = *(const float4*)&krow[h * 256 + (lane << 2)];
      const float4 qv = *(const float4*)&qs[h * 256 + (lane << 2)];
      float s = kv.x * qv.x + kv.y * qv.y + kv.z * qv.z + kv.w * qv.w;
#pragma unroll
      for (int off = 32; off > 0; off >>= 1) s += __shfl_xor(s, off, 64);
      if (lane == 0) sc[n * HH + h] = s * 0.0625f;  // 1/sqrt(256)
    }
  }
  __syncthreads();

  // per-head softmax stats (d <= 128, serial per head is cheap)
  if (t < HH) {
    const int h = t;
    float m = -1e30f;
    for (int n = 0; n < d; ++n) m = fmaxf(m, sc[n * HH + h]);
    float l = 0.f;
    for (int n = 0; n < d; ++n) l += expf(sc[n * HH + h] - m);
    mred[h] = m;
    lred[h] = (l > 0.f) ? 1.f / l : 0.f;
  }
  __syncthreads();

  // convert scores -> probabilities in place
  for (int e = t; e < d * HH; e += 256) {
    const int h = e & (HH - 1);
    sc[e] = expf(sc[e] - mred[h]) * lred[h];
  }
  __syncthreads();

  // aggregate: thread t owns output channel c = t; sum over heads and nbrs
  float accsum = 0.f;
  for (int n = 0; n < d; ++n) {
    const int j = nbr[i * CAP + n];
    const float* vrow = &v[(size_t)j * HC];
#pragma unroll
    for (int h = 0; h < HH; ++h) accsum += sc[n * HH + h] * vrow[h * 256 + t];
  }

  // head mean + skip
  float oval = accsum * 0.125f + skip[(size_t)i * DIMM + t];

  // LayerNorm over the 256 channels of this block
  float s1 = oval, s2 = oval * oval;
#pragma unroll
  for (int off = 32; off > 0; off >>= 1) {
    s1 += __shfl_xor(s1, off, 64);
    s2 += __shfl_xor(s2, off, 64);
  }
  if (lane == 0) { w1[wave] = s1; w2[wave] = s2; }
  __syncthreads();
  const float S1 = w1[0] + w1[1] + w1[2] + w1[3];
  const float S2 = w2[0] + w2[1] + w2[2] + w2[3];
  const float mu = S1 * (1.0f / 256.0f);
  const float var = S2 * (1.0f / 256.0f) - mu * mu;
  const float rst = rsqrtf(var + 1e-5f);

  out[(size_t)i * DIMM + t] =
      (oval - mu) * rst * gamma[t] + beta[t] + x[(size_t)i * DIMM + t];
}

// ---------------------------------------------------------------------------
extern "C" void kernel_launch(void* const* d_in, const int* in_sizes, int n_in,
                              void* d_out, int out_size, void* d_ws, size_t ws_size,
                              hipStream_t stream) {
  const float* x     = (const float*)d_in[0];
  const float* adj   = (const float*)d_in[1];
  const float* Wq    = (const float*)d_in[2];
  const float* bq    = (const float*)d_in[3];
  const float* Wk    = (const float*)d_in[4];
  const float* bk    = (const float*)d_in[5];
  const float* Wv    = (const float*)d_in[6];
  const float* bv    = (const float*)d_in[7];
  const float* Wskip = (const float*)d_in[8];
  const float* bskip = (const float*)d_in[9];
  const float* gamma = (const float*)d_in[10];
  const float* beta  = (const float*)d_in[11];
  float* out = (float*)d_out;

  // workspace layout (f32): q | k | v | skip | deg | nbr   (~102 MB)
  char* ws = (char*)d_ws;
  float* q    = (float*)ws;
  float* kbuf = q + (size_t)NN * HC;
  float* vbuf = kbuf + (size_t)NN * HC;
  float* skip = vbuf + (size_t)NN * HC;
  int* deg = (int*)(skip + (size_t)NN * DIMM);
  int* nbr = deg + NN;

  hipMemsetAsync(deg, 0, NN * sizeof(int), stream);
  build_edges_kernel<<<4096, 256, 0, stream>>>(adj, deg, nbr);

  gemm_bias_kernel<<<dim3(HC / 64, NN / 64), 256, 0, stream>>>(x, Wq, bq, q, NN, HC, DIMM);
  gemm_bias_kernel<<<dim3(HC / 64, NN / 64), 256, 0, stream>>>(x, Wk, bk, kbuf, NN, HC, DIMM);
  gemm_bias_kernel<<<dim3(HC / 64, NN / 64), 256, 0, stream>>>(x, Wv, bv, vbuf, NN, HC, DIMM);
  gemm_bias_kernel<<<dim3(DIMM / 64, NN / 64), 256, 0, stream>>>(x, Wskip, bskip, skip, NN, DIMM, DIMM);

  attn_ln_kernel<<<NN, 256, 0, stream>>>(q, kbuf, vbuf, skip, x, deg, nbr,
                                         gamma, beta, out);
}

// Round 2
// 400.539 us; speedup vs baseline: 1.7540x; 1.7540x over previous
//
#include <hip/hip_runtime.h>
#include <hip/hip_bf16.h>

#define NN   4096
#define DIMM 256
#define HH   8
#define HC   2048   // H * C
#define CAP  128    // max in-degree capacity (binomial(4096,0.01) max ~75)

__device__ __forceinline__ float bfbits(unsigned int u) {
  union { unsigned int u; float f; } un; un.u = u; return un.f;
}
__device__ __forceinline__ unsigned short f2bf(float f) {
  union { float f; unsigned int u; } un; un.f = f;
  unsigned int r = un.u + 0x7fffu + ((un.u >> 16) & 1u);  // RNE
  return (unsigned short)(r >> 16);
}

// ---------------------------------------------------------------------------
// Edge extraction: adj[j*N + i] != 0  =>  edge j -> i (source_to_target).
// ---------------------------------------------------------------------------
__global__ __launch_bounds__(256) void build_edges_kernel(
    const float* __restrict__ adj, int* __restrict__ deg, int* __restrict__ nbr) {
  const int stride = gridDim.x * blockDim.x;
  for (int e = blockIdx.x * blockDim.x + threadIdx.x; e < NN * NN; e += stride) {
    if (adj[e] != 0.0f) {
      const int j = e >> 12;         // source row
      const int i = e & (NN - 1);    // target col
      const int slot = atomicAdd(&deg[i], 1);
      if (slot < CAP) nbr[i * CAP + slot] = j;
    }
  }
}

// ---------------------------------------------------------------------------
// f32 GEMM + bias, templated epilogue (f32 or bf16 store).
// 64x64 block tile, 256 threads, 4x4 register tile, K-tile 16.
// ---------------------------------------------------------------------------
template <int BF16OUT>
__global__ __launch_bounds__(256) void gemm_bias_kernel(
    const float* __restrict__ A, const float* __restrict__ B,
    const float* __restrict__ bias, void* __restrict__ Cv,
    int M, int Nn, int K) {
  __shared__ float As[16][64];
  __shared__ float Bs[16][64];
  const int t = threadIdx.x;
  const int tx = t & 15, ty = t >> 4;
  const int row0 = blockIdx.y * 64, col0 = blockIdx.x * 64;
  const int ra = t >> 2, ca = (t & 3) << 2;    // A-tile load coords
  const int rb = t >> 4, cb = (t & 15) << 2;   // B-tile load coords

  float acc[4][4] = {{0.f, 0.f, 0.f, 0.f}, {0.f, 0.f, 0.f, 0.f},
                     {0.f, 0.f, 0.f, 0.f}, {0.f, 0.f, 0.f, 0.f}};

  for (int kt = 0; kt < K; kt += 16) {
    const float4 av = *(const float4*)&A[(size_t)(row0 + ra) * K + kt + ca];
    const float4 bv = *(const float4*)&B[(size_t)(kt + rb) * Nn + col0 + cb];
    As[ca + 0][ra] = av.x;
    As[ca + 1][ra] = av.y;
    As[ca + 2][ra] = av.z;
    As[ca + 3][ra] = av.w;
    *(float4*)&Bs[rb][cb] = bv;
    __syncthreads();
#pragma unroll
    for (int kk = 0; kk < 16; ++kk) {
      const float4 a4 = *(const float4*)&As[kk][ty << 2];
      const float4 b4 = *(const float4*)&Bs[kk][tx << 2];
      const float aa[4] = {a4.x, a4.y, a4.z, a4.w};
      const float bb[4] = {b4.x, b4.y, b4.z, b4.w};
#pragma unroll
      for (int ii = 0; ii < 4; ++ii)
#pragma unroll
        for (int jj = 0; jj < 4; ++jj)
          acc[ii][jj] = fmaf(aa[ii], bb[jj], acc[ii][jj]);
    }
    __syncthreads();
  }

  const float4 bvec = *(const float4*)&bias[col0 + (tx << 2)];
#pragma unroll
  for (int ii = 0; ii < 4; ++ii) {
    float o0 = acc[ii][0] + bvec.x;
    float o1 = acc[ii][1] + bvec.y;
    float o2 = acc[ii][2] + bvec.z;
    float o3 = acc[ii][3] + bvec.w;
    const size_t off = (size_t)(row0 + (ty << 2) + ii) * Nn + col0 + (tx << 2);
    if (BF16OUT) {
      ushort4 o;
      o.x = f2bf(o0); o.y = f2bf(o1); o.z = f2bf(o2); o.w = f2bf(o3);
      *(ushort4*)&((unsigned short*)Cv)[off] = o;
    } else {
      float4 o = {o0, o1, o2, o3};
      *(float4*)&((float*)Cv)[off] = o;
    }
  }
}

// ---------------------------------------------------------------------------
// Sparse attention (bf16 q/k/v) + head-mean + skip + LayerNorm + residual.
// One block (256 threads = 4 waves) per target node i.
//   Score phase: lane l -> head l>>3, 32-elem slice l&7; 3-step shfl reduce.
//   Aggregate:   wave-strided edges; lane owns 4 output channels.
// ---------------------------------------------------------------------------
__global__ __launch_bounds__(256) void attn_ln_kernel(
    const unsigned short* __restrict__ q, const unsigned short* __restrict__ k,
    const unsigned short* __restrict__ v, const float* __restrict__ skip,
    const float* __restrict__ x, const int* __restrict__ deg,
    const int* __restrict__ nbr, const float* __restrict__ gamma,
    const float* __restrict__ beta, float* __restrict__ out) {
  const int i = blockIdx.x;
  const int t = threadIdx.x;
  const int lane = t & 63, wave = t >> 6;
  const int h = lane >> 3, sub = lane & 7;   // score-phase mapping

  __shared__ int slist[CAP];
  __shared__ float sc[CAP * HH];
  __shared__ float wacc[4][DIMM];
  __shared__ float mred[HH], lred[HH];
  __shared__ float w1[4], w2[4];

  int d = deg[i];
  if (d > CAP) d = CAP;

  // ---- load + bitonic-sort neighbor list in LDS (deterministic order) ----
  if (t < CAP) slist[t] = (t < d) ? nbr[i * CAP + t] : 0x7fffffff;
  __syncthreads();
  for (int ksz = 2; ksz <= CAP; ksz <<= 1) {
    for (int jsz = ksz >> 1; jsz > 0; jsz >>= 1) {
      if (t < CAP) {
        const int ixj = t ^ jsz;
        if (ixj > t) {
          const int a = slist[t], b = slist[ixj];
          const bool up = ((t & ksz) == 0);
          if ((up && a > b) || (!up && a < b)) { slist[t] = b; slist[ixj] = a; }
        }
      }
      __syncthreads();
    }
  }

  // ---- hoist q slice (32 elems of head h) into registers as f32 ----
  float qf[32];
  {
    const uint4* qp = (const uint4*)&q[(size_t)i * HC + (h << 8) + (sub << 5)];
#pragma unroll
    for (int b = 0; b < 4; ++b) {
      const uint4 w = qp[b];
      qf[b * 8 + 0] = bfbits(w.x << 16); qf[b * 8 + 1] = bfbits(w.x & 0xffff0000u);
      qf[b * 8 + 2] = bfbits(w.y << 16); qf[b * 8 + 3] = bfbits(w.y & 0xffff0000u);
      qf[b * 8 + 4] = bfbits(w.z << 16); qf[b * 8 + 5] = bfbits(w.z & 0xffff0000u);
      qf[b * 8 + 6] = bfbits(w.w << 16); qf[b * 8 + 7] = bfbits(w.w & 0xffff0000u);
    }
  }

  // ---- scores: wave-strided edges; per edge: 8-lane-group dot of 256 ----
  for (int n = wave; n < d; n += 4) {
    const int j = slist[n];
    const uint4* kp = (const uint4*)&k[(size_t)j * HC + (h << 8) + (sub << 5)];
    float s = 0.f;
#pragma unroll
    for (int b = 0; b < 4; ++b) {
      const uint4 w = kp[b];
      s += qf[b * 8 + 0] * bfbits(w.x << 16) + qf[b * 8 + 1] * bfbits(w.x & 0xffff0000u);
      s += qf[b * 8 + 2] * bfbits(w.y << 16) + qf[b * 8 + 3] * bfbits(w.y & 0xffff0000u);
      s += qf[b * 8 + 4] * bfbits(w.z << 16) + qf[b * 8 + 5] * bfbits(w.z & 0xffff0000u);
      s += qf[b * 8 + 6] * bfbits(w.w << 16) + qf[b * 8 + 7] * bfbits(w.w & 0xffff0000u);
    }
    s += __shfl_xor(s, 1);
    s += __shfl_xor(s, 2);
    s += __shfl_xor(s, 4);
    if (sub == 0) sc[n * HH + h] = s * 0.0625f;  // 1/sqrt(256)
  }
  __syncthreads();

  // ---- per-head softmax stats ----
  if (t < HH) {
    float m = -1e30f;
    for (int n = 0; n < d; ++n) m = fmaxf(m, sc[n * HH + t]);
    float l = 0.f;
    for (int n = 0; n < d; ++n) l += expf(sc[n * HH + t] - m);
    mred[t] = m;
    lred[t] = (l > 0.f) ? 1.f / l : 0.f;
  }
  __syncthreads();

  // ---- scores -> probabilities ----
  for (int e = t; e < d * HH; e += 256) {
    const int hh = e & (HH - 1);
    sc[e] = expf(sc[e] - mred[hh]) * lred[hh];
  }
  __syncthreads();

  // ---- aggregate: wave-strided edges; lane owns channels 4*lane..+3 ----
  float a0 = 0.f, a1 = 0.f, a2 = 0.f, a3 = 0.f;
  for (int n = wave; n < d; n += 4) {
    const int j = slist[n];
    float p[HH];
#pragma unroll
    for (int hh = 0; hh < HH; ++hh) p[hh] = sc[n * HH + hh];
    const unsigned short* vr = &v[(size_t)j * HC + (lane << 2)];
#pragma unroll
    for (int hh = 0; hh < HH; ++hh) {
      const uint2 w = *(const uint2*)&vr[hh << 8];
      a0 = fmaf(p[hh], bfbits(w.x << 16), a0);
      a1 = fmaf(p[hh], bfbits(w.x & 0xffff0000u), a1);
      a2 = fmaf(p[hh], bfbits(w.y << 16), a2);
      a3 = fmaf(p[hh], bfbits(w.y & 0xffff0000u), a3);
    }
  }
  wacc[wave][(lane << 2) + 0] = a0;
  wacc[wave][(lane << 2) + 1] = a1;
  wacc[wave][(lane << 2) + 2] = a2;
  wacc[wave][(lane << 2) + 3] = a3;
  __syncthreads();

  // ---- head mean + skip + LayerNorm + residual (thread t = channel t) ----
  const float accsum = wacc[0][t] + wacc[1][t] + wacc[2][t] + wacc[3][t];
  const float oval = accsum * 0.125f + skip[(size_t)i * DIMM + t];

  float s1 = oval, s2 = oval * oval;
#pragma unroll
  for (int off = 32; off > 0; off >>= 1) {
    s1 += __shfl_xor(s1, off, 64);
    s2 += __shfl_xor(s2, off, 64);
  }
  if (lane == 0) { w1[wave] = s1; w2[wave] = s2; }
  __syncthreads();
  const float S1 = w1[0] + w1[1] + w1[2] + w1[3];
  const float S2 = w2[0] + w2[1] + w2[2] + w2[3];
  const float mu = S1 * (1.0f / 256.0f);
  const float var = S2 * (1.0f / 256.0f) - mu * mu;
  const float rst = rsqrtf(var + 1e-5f);

  out[(size_t)i * DIMM + t] =
      (oval - mu) * rst * gamma[t] + beta[t] + x[(size_t)i * DIMM + t];
}

// ---------------------------------------------------------------------------
extern "C" void kernel_launch(void* const* d_in, const int* in_sizes, int n_in,
                              void* d_out, int out_size, void* d_ws, size_t ws_size,
                              hipStream_t stream) {
  const float* x     = (const float*)d_in[0];
  const float* adj   = (const float*)d_in[1];
  const float* Wq    = (const float*)d_in[2];
  const float* bq    = (const float*)d_in[3];
  const float* Wk    = (const float*)d_in[4];
  const float* bk    = (const float*)d_in[5];
  const float* Wv    = (const float*)d_in[6];
  const float* bv    = (const float*)d_in[7];
  const float* Wskip = (const float*)d_in[8];
  const float* bskip = (const float*)d_in[9];
  const float* gamma = (const float*)d_in[10];
  const float* beta  = (const float*)d_in[11];
  float* out = (float*)d_out;

  // workspace layout: q | k | v (bf16) | skip (f32) | deg | nbr  (~54 MB)
  char* ws = (char*)d_ws;
  unsigned short* qb = (unsigned short*)ws;
  unsigned short* kb = qb + (size_t)NN * HC;
  unsigned short* vb = kb + (size_t)NN * HC;
  float* skip = (float*)(vb + (size_t)NN * HC);
  int* deg = (int*)(skip + (size_t)NN * DIMM);
  int* nbr = deg + NN;

  hipMemsetAsync(deg, 0, NN * sizeof(int), stream);
  build_edges_kernel<<<4096, 256, 0, stream>>>(adj, deg, nbr);

  gemm_bias_kernel<1><<<dim3(HC / 64, NN / 64), 256, 0, stream>>>(x, Wq, bq, qb, NN, HC, DIMM);
  gemm_bias_kernel<1><<<dim3(HC / 64, NN / 64), 256, 0, stream>>>(x, Wk, bk, kb, NN, HC, DIMM);
  gemm_bias_kernel<1><<<dim3(HC / 64, NN / 64), 256, 0, stream>>>(x, Wv, bv, vb, NN, HC, DIMM);
  gemm_bias_kernel<0><<<dim3(DIMM / 64, NN / 64), 256, 0, stream>>>(x, Wskip, bskip, skip, NN, DIMM, DIMM);

  attn_ln_kernel<<<NN, 256, 0, stream>>>(qb, kb, vb, skip, x, deg, nbr,
                                         gamma, beta, out);
}

// Round 3
// 233.453 us; speedup vs baseline: 3.0094x; 1.7157x over previous
//
#include <hip/hip_runtime.h>
#include <hip/hip_bf16.h>

#define NN   4096
#define DIMM 256
#define HH   8
#define HC   2048   // H * C
#define CAP  128    // max in-degree capacity

typedef short  bf16x8 __attribute__((ext_vector_type(8)));
typedef float  f32x4  __attribute__((ext_vector_type(4)));

__device__ __forceinline__ float bfbits(unsigned int u) {
  union { unsigned int u; float f; } un; un.u = u; return un.f;
}
__device__ __forceinline__ unsigned short f2bf(float f) {
  union { float f; unsigned int u; } un; un.f = f;
  unsigned int r = un.u + 0x7fffu + ((un.u >> 16) & 1u);  // RNE
  return (unsigned short)(r >> 16);
}
__device__ __forceinline__ void gload16(const void* g, void* l) {
  __builtin_amdgcn_global_load_lds(
      (const __attribute__((address_space(1))) unsigned int*)g,
      (__attribute__((address_space(3))) unsigned int*)l, 16, 0, 0);
}

// ---------------------------------------------------------------------------
// Edge extraction (float4-vectorized): adj[j*N + i] != 0 => edge j -> i.
// ---------------------------------------------------------------------------
__global__ __launch_bounds__(256) void build_edges_kernel(
    const float4* __restrict__ adj4, int* __restrict__ deg, int* __restrict__ nbr) {
  const int stride = gridDim.x * blockDim.x;
  for (int e4 = blockIdx.x * blockDim.x + threadIdx.x; e4 < NN * NN / 4; e4 += stride) {
    const float4 a = adj4[e4];
    if (a.x != 0.f || a.y != 0.f || a.z != 0.f || a.w != 0.f) {
      const int e = e4 << 2;
      const int j = e >> 12;            // source row
      const int ib = e & (NN - 1);      // target col base
      if (a.x != 0.f) { int s = atomicAdd(&deg[ib + 0], 1); if (s < CAP) nbr[(ib + 0) * CAP + s] = j; }
      if (a.y != 0.f) { int s = atomicAdd(&deg[ib + 1], 1); if (s < CAP) nbr[(ib + 1) * CAP + s] = j; }
      if (a.z != 0.f) { int s = atomicAdd(&deg[ib + 2], 1); if (s < CAP) nbr[(ib + 2) * CAP + s] = j; }
      if (a.w != 0.f) { int s = atomicAdd(&deg[ib + 3], 1); if (s < CAP) nbr[(ib + 3) * CAP + s] = j; }
    }
  }
}

// ---------------------------------------------------------------------------
// x cast: f32 [M][K=256] -> bf16 [M][K] with XOR chunk-swizzle baked:
// within each 64-elem K-block, 8-elem chunk c stored at c ^ (m&7).
// ---------------------------------------------------------------------------
__global__ __launch_bounds__(256) void cast_x_kernel(
    const float* __restrict__ x, unsigned short* __restrict__ xb) {
  const int gid = blockIdx.x * 256 + threadIdx.x;  // [0, 4096*32)
  const int m = gid >> 5, c = gid & 31;
  const float4 a = *(const float4*)&x[(size_t)m * 256 + c * 8];
  const float4 b = *(const float4*)&x[(size_t)m * 256 + c * 8 + 4];
  union { unsigned short u[8]; uint4 v; } o;
  o.u[0] = f2bf(a.x); o.u[1] = f2bf(a.y); o.u[2] = f2bf(a.z); o.u[3] = f2bf(a.w);
  o.u[4] = f2bf(b.x); o.u[5] = f2bf(b.y); o.u[6] = f2bf(b.z); o.u[7] = f2bf(b.w);
  const int cs = (c & 24) | ((c & 7) ^ (m & 7));
  *(uint4*)&xb[(size_t)m * 256 + cs * 8] = o.v;
}

// ---------------------------------------------------------------------------
// Weight transpose+cast: W f32 [K=256][Nw] -> T bf16 [Nw][256] with the same
// XOR chunk-swizzle on K (keyed by output row n&7). LDS-tiled 64x64.
// ---------------------------------------------------------------------------
__global__ __launch_bounds__(256) void tcast_w_kernel(
    const float* __restrict__ W0, const float* __restrict__ W1,
    const float* __restrict__ W2, unsigned short* __restrict__ T0,
    unsigned short* __restrict__ T1, unsigned short* __restrict__ T2, int Nw) {
  const float* W = blockIdx.z == 0 ? W0 : blockIdx.z == 1 ? W1 : W2;
  unsigned short* T = blockIdx.z == 0 ? T0 : blockIdx.z == 1 ? T1 : T2;
  __shared__ float Tf[64][68];
  const int t = threadIdx.x;
  const int n0 = blockIdx.x * 64, k0 = blockIdx.y * 64;
  const int kk0 = t >> 4, nc = t & 15;
#pragma unroll
  for (int r = 0; r < 4; ++r) {
    const int kk = kk0 + r * 16;
    const float4 a = *(const float4*)&W[(size_t)(k0 + kk) * Nw + n0 + nc * 4];
    Tf[kk][nc * 4 + 0] = a.x; Tf[kk][nc * 4 + 1] = a.y;
    Tf[kk][nc * 4 + 2] = a.z; Tf[kk][nc * 4 + 3] = a.w;
  }
  __syncthreads();
  const int n = t >> 2, cp = t & 3;
#pragma unroll
  for (int qq = 0; qq < 2; ++qq) {
    const int cc = cp * 2 + qq;            // chunk within the 64-k block
    union { unsigned short u[8]; uint4 v; } o;
#pragma unroll
    for (int e = 0; e < 8; ++e) o.u[e] = f2bf(Tf[cc * 8 + e][n]);
    const int ng = n0 + n;
    const int co = cc ^ (ng & 7);
    *(uint4*)&T[(size_t)ng * 256 + blockIdx.y * 64 + co * 8] = o.v;
  }
}

// ---------------------------------------------------------------------------
// bf16 MFMA GEMM + bias: C[M x Nc] = Abf[M x 256] @ T^T (+bias)
// 128x128 tile, BK=64, 4 waves (each 64x64 = 4x4 frags of 16x16x32).
// A and T both [row][256] bf16 with XOR chunk-swizzle; staged linearly via
// global_load_lds(16B); frag ds_read applies the same XOR -> conflict-free.
// ---------------------------------------------------------------------------
template <int BF16OUT>
__global__ __launch_bounds__(256) void mfma_gemm_kernel(
    const unsigned short* __restrict__ Abf,
    const unsigned short* __restrict__ B0, const unsigned short* __restrict__ B1,
    const unsigned short* __restrict__ B2,
    const float* __restrict__ bias0, const float* __restrict__ bias1,
    const float* __restrict__ bias2,
    void* __restrict__ C0v, void* __restrict__ C1v, void* __restrict__ C2v,
    int Nc) {
  const unsigned short* Bm = blockIdx.z == 0 ? B0 : blockIdx.z == 1 ? B1 : B2;
  const float* bias = blockIdx.z == 0 ? bias0 : blockIdx.z == 1 ? bias1 : bias2;
  void* Cv = blockIdx.z == 0 ? C0v : blockIdx.z == 1 ? C1v : C2v;

  __shared__ unsigned short lds[2 * 128 * 64];   // 32 KiB
  unsigned short* As = lds;                       // [128 rows][64 k]
  unsigned short* Bs = lds + 128 * 64;            // [128 n-rows][64 k]

  const int t = threadIdx.x, l = t & 63, w = t >> 6;
  const int m0 = blockIdx.y * 128, n0 = blockIdx.x * 128;
  const int wm = w >> 1, wn = w & 1;              // wave -> 64x64 sub-tile

  const f32x4 zero = {0.f, 0.f, 0.f, 0.f};
  f32x4 acc[4][4];
#pragma unroll
  for (int fm = 0; fm < 4; ++fm)
#pragma unroll
    for (int fn = 0; fn < 4; ++fn) acc[fm][fn] = zero;

  for (int kb = 0; kb < 4; ++kb) {
#pragma unroll
    for (int r = 0; r < 4; ++r) {
      const int rr = r * 8 + (l >> 3), ch = l & 7;
      gload16(Abf + (size_t)(m0 + w * 32 + rr) * 256 + kb * 64 + ch * 8,
              As + w * 2048 + r * 512);
      gload16(Bm + (size_t)(n0 + w * 32 + rr) * 256 + kb * 64 + ch * 8,
              Bs + w * 2048 + r * 512);
    }
    __syncthreads();

#pragma unroll
    for (int s = 0; s < 2; ++s) {
      const int chab = (4 * s + (l >> 4)) ^ (l & 7);
      bf16x8 af[4], bfr[4];
#pragma unroll
      for (int fm = 0; fm < 4; ++fm) {
        const int row = wm * 64 + fm * 16 + (l & 15);
        af[fm] = *(const bf16x8*)&As[row * 64 + chab * 8];
      }
#pragma unroll
      for (int fn = 0; fn < 4; ++fn) {
        const int row = wn * 64 + fn * 16 + (l & 15);
        bfr[fn] = *(const bf16x8*)&Bs[row * 64 + chab * 8];
      }
#pragma unroll
      for (int fm = 0; fm < 4; ++fm)
#pragma unroll
        for (int fn = 0; fn < 4; ++fn)
          acc[fm][fn] = __builtin_amdgcn_mfma_f32_16x16x32_bf16(
              af[fm], bfr[fn], acc[fm][fn], 0, 0, 0);
    }
    __syncthreads();
  }

  // bias per fn (col = n0 + wn*64 + fn*16 + (l&15))
  float bv[4];
#pragma unroll
  for (int fn = 0; fn < 4; ++fn) bv[fn] = bias[n0 + wn * 64 + fn * 16 + (l & 15)];

  if (BF16OUT) {
    unsigned short* Cc = (unsigned short*)Cv;
    // stage into LDS [128][128] ushort (exactly 32 KiB), chunk-XOR by row&15
#pragma unroll
    for (int fm = 0; fm < 4; ++fm) {
      const int colc = wn * 64 + (l & 15);
#pragma unroll
      for (int fn = 0; fn < 4; ++fn) {
        const int col = colc + fn * 16;
#pragma unroll
        for (int r = 0; r < 4; ++r) {
          const int row = wm * 64 + fm * 16 + (l >> 4) * 4 + r;
          const int pos = ((col >> 3) ^ (row & 15)) * 8 + (col & 7);
          lds[row * 128 + pos] = f2bf(acc[fm][fn][r] + bv[fn]);
        }
      }
    }
    __syncthreads();
#pragma unroll
    for (int r2 = 0; r2 < 8; ++r2) {
      const int idx = r2 * 256 + t;
      const int row = idx >> 4, ch = idx & 15;
      *(uint4*)&Cc[(size_t)(m0 + row) * Nc + n0 + ch * 8] =
          *(const uint4*)&lds[row * 128 + (ch ^ (row & 15)) * 8];
    }
  } else {
    float* Cc = (float*)Cv;
#pragma unroll
    for (int fm = 0; fm < 4; ++fm)
#pragma unroll
      for (int fn = 0; fn < 4; ++fn)
#pragma unroll
        for (int r = 0; r < 4; ++r) {
          const int row = wm * 64 + fm * 16 + (l >> 4) * 4 + r;
          const int col = wn * 64 + fn * 16 + (l & 15);
          Cc[(size_t)(m0 + row) * Nc + n0 + col] = acc[fm][fn][r] + bv[fn];
        }
  }
}

// ---------------------------------------------------------------------------
// Sparse attention (bf16 q/k/v) + head-mean + skip + LayerNorm + residual.
// (unchanged from previous round)
// ---------------------------------------------------------------------------
__global__ __launch_bounds__(256) void attn_ln_kernel(
    const unsigned short* __restrict__ q, const unsigned short* __restrict__ k,
    const unsigned short* __restrict__ v, const float* __restrict__ skip,
    const float* __restrict__ x, const int* __restrict__ deg,
    const int* __restrict__ nbr, const float* __restrict__ gamma,
    const float* __restrict__ beta, float* __restrict__ out) {
  const int i = blockIdx.x;
  const int t = threadIdx.x;
  const int lane = t & 63, wave = t >> 6;
  const int h = lane >> 3, sub = lane & 7;

  __shared__ int slist[CAP];
  __shared__ float sc[CAP * HH];
  __shared__ float wacc[4][DIMM];
  __shared__ float mred[HH], lred[HH];
  __shared__ float w1[4], w2[4];

  int d = deg[i];
  if (d > CAP) d = CAP;

  if (t < CAP) slist[t] = (t < d) ? nbr[i * CAP + t] : 0x7fffffff;
  __syncthreads();
  for (int ksz = 2; ksz <= CAP; ksz <<= 1) {
    for (int jsz = ksz >> 1; jsz > 0; jsz >>= 1) {
      if (t < CAP) {
        const int ixj = t ^ jsz;
        if (ixj > t) {
          const int a = slist[t], b = slist[ixj];
          const bool up = ((t & ksz) == 0);
          if ((up && a > b) || (!up && a < b)) { slist[t] = b; slist[ixj] = a; }
        }
      }
      __syncthreads();
    }
  }

  float qf[32];
  {
    const uint4* qp = (const uint4*)&q[(size_t)i * HC + (h << 8) + (sub << 5)];
#pragma unroll
    for (int b = 0; b < 4; ++b) {
      const uint4 w = qp[b];
      qf[b * 8 + 0] = bfbits(w.x << 16); qf[b * 8 + 1] = bfbits(w.x & 0xffff0000u);
      qf[b * 8 + 2] = bfbits(w.y << 16); qf[b * 8 + 3] = bfbits(w.y & 0xffff0000u);
      qf[b * 8 + 4] = bfbits(w.z << 16); qf[b * 8 + 5] = bfbits(w.z & 0xffff0000u);
      qf[b * 8 + 6] = bfbits(w.w << 16); qf[b * 8 + 7] = bfbits(w.w & 0xffff0000u);
    }
  }

  for (int n = wave; n < d; n += 4) {
    const int j = slist[n];
    const uint4* kp = (const uint4*)&k[(size_t)j * HC + (h << 8) + (sub << 5)];
    float s = 0.f;
#pragma unroll
    for (int b = 0; b < 4; ++b) {
      const uint4 w = kp[b];
      s += qf[b * 8 + 0] * bfbits(w.x << 16) + qf[b * 8 + 1] * bfbits(w.x & 0xffff0000u);
      s += qf[b * 8 + 2] * bfbits(w.y << 16) + qf[b * 8 + 3] * bfbits(w.y & 0xffff0000u);
      s += qf[b * 8 + 4] * bfbits(w.z << 16) + qf[b * 8 + 5] * bfbits(w.z & 0xffff0000u);
      s += qf[b * 8 + 6] * bfbits(w.w << 16) + qf[b * 8 + 7] * bfbits(w.w & 0xffff0000u);
    }
    s += __shfl_xor(s, 1);
    s += __shfl_xor(s, 2);
    s += __shfl_xor(s, 4);
    if (sub == 0) sc[n * HH + h] = s * 0.0625f;
  }
  __syncthreads();

  if (t < HH) {
    float m = -1e30f;
    for (int n = 0; n < d; ++n) m = fmaxf(m, sc[n * HH + t]);
    float lsum = 0.f;
    for (int n = 0; n < d; ++n) lsum += expf(sc[n * HH + t] - m);
    mred[t] = m;
    lred[t] = (lsum > 0.f) ? 1.f / lsum : 0.f;
  }
  __syncthreads();

  for (int e = t; e < d * HH; e += 256) {
    const int hh = e & (HH - 1);
    sc[e] = expf(sc[e] - mred[hh]) * lred[hh];
  }
  __syncthreads();

  float a0 = 0.f, a1 = 0.f, a2 = 0.f, a3 = 0.f;
  for (int n = wave; n < d; n += 4) {
    const int j = slist[n];
    float p[HH];
#pragma unroll
    for (int hh = 0; hh < HH; ++hh) p[hh] = sc[n * HH + hh];
    const unsigned short* vr = &v[(size_t)j * HC + (lane << 2)];
#pragma unroll
    for (int hh = 0; hh < HH; ++hh) {
      const uint2 w = *(const uint2*)&vr[hh << 8];
      a0 = fmaf(p[hh], bfbits(w.x << 16), a0);
      a1 = fmaf(p[hh], bfbits(w.x & 0xffff0000u), a1);
      a2 = fmaf(p[hh], bfbits(w.y << 16), a2);
      a3 = fmaf(p[hh], bfbits(w.y & 0xffff0000u), a3);
    }
  }
  wacc[wave][(lane << 2) + 0] = a0;
  wacc[wave][(lane << 2) + 1] = a1;
  wacc[wave][(lane << 2) + 2] = a2;
  wacc[wave][(lane << 2) + 3] = a3;
  __syncthreads();

  const float accsum = wacc[0][t] + wacc[1][t] + wacc[2][t] + wacc[3][t];
  const float oval = accsum * 0.125f + skip[(size_t)i * DIMM + t];

  float s1 = oval, s2 = oval * oval;
#pragma unroll
  for (int off = 32; off > 0; off >>= 1) {
    s1 += __shfl_xor(s1, off, 64);
    s2 += __shfl_xor(s2, off, 64);
  }
  if (lane == 0) { w1[wave] = s1; w2[wave] = s2; }
  __syncthreads();
  const float S1 = w1[0] + w1[1] + w1[2] + w1[3];
  const float S2 = w2[0] + w2[1] + w2[2] + w2[3];
  const float mu = S1 * (1.0f / 256.0f);
  const float var = S2 * (1.0f / 256.0f) - mu * mu;
  const float rst = rsqrtf(var + 1e-5f);

  out[(size_t)i * DIMM + t] =
      (oval - mu) * rst * gamma[t] + beta[t] + x[(size_t)i * DIMM + t];
}

// ---------------------------------------------------------------------------
extern "C" void kernel_launch(void* const* d_in, const int* in_sizes, int n_in,
                              void* d_out, int out_size, void* d_ws, size_t ws_size,
                              hipStream_t stream) {
  const float* x     = (const float*)d_in[0];
  const float* adj   = (const float*)d_in[1];
  const float* Wq    = (const float*)d_in[2];
  const float* bq    = (const float*)d_in[3];
  const float* Wk    = (const float*)d_in[4];
  const float* bk    = (const float*)d_in[5];
  const float* Wv    = (const float*)d_in[6];
  const float* bv    = (const float*)d_in[7];
  const float* Wskip = (const float*)d_in[8];
  const float* bskip = (const float*)d_in[9];
  const float* gamma = (const float*)d_in[10];
  const float* beta  = (const float*)d_in[11];
  float* out = (float*)d_out;

  // workspace: xb | WqT | WkT | WvT | WsT | qb | kb | vb (bf16) | skip f32 | deg | nbr
  char* ws = (char*)d_ws;
  unsigned short* xb  = (unsigned short*)ws;
  unsigned short* WqT = xb  + (size_t)NN * DIMM;
  unsigned short* WkT = WqT + (size_t)HC * DIMM;
  unsigned short* WvT = WkT + (size_t)HC * DIMM;
  unsigned short* WsT = WvT + (size_t)HC * DIMM;
  unsigned short* qb  = WsT + (size_t)DIMM * DIMM;
  unsigned short* kbf = qb  + (size_t)NN * HC;
  unsigned short* vbf = kbf + (size_t)NN * HC;
  float* skip = (float*)(vbf + (size_t)NN * HC);
  int* deg = (int*)(skip + (size_t)NN * DIMM);
  int* nbr = deg + NN;

  hipMemsetAsync(deg, 0, NN * sizeof(int), stream);
  build_edges_kernel<<<2048, 256, 0, stream>>>((const float4*)adj, deg, nbr);

  cast_x_kernel<<<NN * 32 / 256, 256, 0, stream>>>(x, xb);
  tcast_w_kernel<<<dim3(HC / 64, 4, 3), 256, 0, stream>>>(Wq, Wk, Wv, WqT, WkT, WvT, HC);
  tcast_w_kernel<<<dim3(DIMM / 64, 4, 1), 256, 0, stream>>>(Wskip, Wskip, Wskip,
                                                            WsT, WsT, WsT, DIMM);

  mfma_gemm_kernel<1><<<dim3(HC / 128, NN / 128, 3), 256, 0, stream>>>(
      xb, WqT, WkT, WvT, bq, bk, bv, qb, kbf, vbf, HC);
  mfma_gemm_kernel<0><<<dim3(DIMM / 128, NN / 128, 1), 256, 0, stream>>>(
      xb, WsT, WsT, WsT, bskip, bskip, bskip, skip, skip, skip, DIMM);

  attn_ln_kernel<<<NN, 256, 0, stream>>>(qb, kbf, vbf, skip, x, deg, nbr,
                                         gamma, beta, out);
}

// Round 4
// 155.914 us; speedup vs baseline: 4.5060x; 1.4973x over previous
//
#include <hip/hip_runtime.h>
#include <hip/hip_bf16.h>

#define NN   4096
#define DIMM 256
#define HH   8
#define HC   2048   // H * C
#define CAP  128    // max in-degree capacity

typedef short  bf16x8 __attribute__((ext_vector_type(8)));
typedef float  f32x4  __attribute__((ext_vector_type(4)));
typedef float  f32x2  __attribute__((ext_vector_type(2)));

__device__ __forceinline__ float bfbits(unsigned int u) {
  union { unsigned int u; float f; } un; un.u = u; return un.f;
}
__device__ __forceinline__ unsigned short f2bf(float f) {
  union { float f; unsigned int u; } un; un.f = f;
  unsigned int r = un.u + 0x7fffu + ((un.u >> 16) & 1u);  // RNE
  return (unsigned short)(r >> 16);
}
__device__ __forceinline__ void gload16(const void* g, void* l) {
  __builtin_amdgcn_global_load_lds(
      (const __attribute__((address_space(1))) unsigned int*)g,
      (__attribute__((address_space(3))) unsigned int*)l, 16, 0, 0);
}

// ---------------------------------------------------------------------------
// Edge extraction (float4-vectorized): adj[j*N + i] != 0 => edge j -> i.
// ---------------------------------------------------------------------------
__global__ __launch_bounds__(256) void build_edges_kernel(
    const float4* __restrict__ adj4, int* __restrict__ deg, int* __restrict__ nbr) {
  const int stride = gridDim.x * blockDim.x;
  for (int e4 = blockIdx.x * blockDim.x + threadIdx.x; e4 < NN * NN / 4; e4 += stride) {
    const float4 a = adj4[e4];
    if (a.x != 0.f || a.y != 0.f || a.z != 0.f || a.w != 0.f) {
      const int e = e4 << 2;
      const int j = e >> 12;            // source row
      const int ib = e & (NN - 1);      // target col base
      if (a.x != 0.f) { int s = atomicAdd(&deg[ib + 0], 1); if (s < CAP) nbr[(ib + 0) * CAP + s] = j; }
      if (a.y != 0.f) { int s = atomicAdd(&deg[ib + 1], 1); if (s < CAP) nbr[(ib + 1) * CAP + s] = j; }
      if (a.z != 0.f) { int s = atomicAdd(&deg[ib + 2], 1); if (s < CAP) nbr[(ib + 2) * CAP + s] = j; }
      if (a.w != 0.f) { int s = atomicAdd(&deg[ib + 3], 1); if (s < CAP) nbr[(ib + 3) * CAP + s] = j; }
    }
  }
}

// ---------------------------------------------------------------------------
// Per-node bitonic sort of neighbor lists (deterministic summation order).
// ---------------------------------------------------------------------------
__global__ __launch_bounds__(128) void sort_nbr_kernel(
    const int* __restrict__ deg, int* __restrict__ nbr) {
  const int i = blockIdx.x, t = threadIdx.x;
  __shared__ int sl[CAP];
  int d = deg[i];
  if (d > CAP) d = CAP;
  if (d <= 1) return;
  sl[t] = (t < d) ? nbr[i * CAP + t] : 0x7fffffff;
  __syncthreads();
  for (int ksz = 2; ksz <= CAP; ksz <<= 1) {
    for (int jsz = ksz >> 1; jsz > 0; jsz >>= 1) {
      const int ixj = t ^ jsz;
      if (ixj > t) {
        const int a = sl[t], b = sl[ixj];
        const bool up = ((t & ksz) == 0);
        if ((up && a > b) || (!up && a < b)) { sl[t] = b; sl[ixj] = a; }
      }
      __syncthreads();
    }
  }
  if (t < d) nbr[i * CAP + t] = sl[t];
}

// ---------------------------------------------------------------------------
// x cast: f32 [M][K=256] -> bf16 [M][K] with XOR chunk-swizzle baked.
// ---------------------------------------------------------------------------
__global__ __launch_bounds__(256) void cast_x_kernel(
    const float* __restrict__ x, unsigned short* __restrict__ xb) {
  const int gid = blockIdx.x * 256 + threadIdx.x;  // [0, 4096*32)
  const int m = gid >> 5, c = gid & 31;
  const float4 a = *(const float4*)&x[(size_t)m * 256 + c * 8];
  const float4 b = *(const float4*)&x[(size_t)m * 256 + c * 8 + 4];
  union { unsigned short u[8]; uint4 v; } o;
  o.u[0] = f2bf(a.x); o.u[1] = f2bf(a.y); o.u[2] = f2bf(a.z); o.u[3] = f2bf(a.w);
  o.u[4] = f2bf(b.x); o.u[5] = f2bf(b.y); o.u[6] = f2bf(b.z); o.u[7] = f2bf(b.w);
  const int cs = (c & 24) | ((c & 7) ^ (m & 7));
  *(uint4*)&xb[(size_t)m * 256 + cs * 8] = o.v;
}

// ---------------------------------------------------------------------------
// Weight transpose+cast: W f32 [K=256][Nw] -> T bf16 [Nw][256], XOR-swizzled.
// ---------------------------------------------------------------------------
__global__ __launch_bounds__(256) void tcast_w_kernel(
    const float* __restrict__ W0, const float* __restrict__ W1,
    const float* __restrict__ W2, unsigned short* __restrict__ T0,
    unsigned short* __restrict__ T1, unsigned short* __restrict__ T2, int Nw) {
  const float* W = blockIdx.z == 0 ? W0 : blockIdx.z == 1 ? W1 : W2;
  unsigned short* T = blockIdx.z == 0 ? T0 : blockIdx.z == 1 ? T1 : T2;
  __shared__ float Tf[64][68];
  const int t = threadIdx.x;
  const int n0 = blockIdx.x * 64, k0 = blockIdx.y * 64;
  const int kk0 = t >> 4, nc = t & 15;
#pragma unroll
  for (int r = 0; r < 4; ++r) {
    const int kk = kk0 + r * 16;
    const float4 a = *(const float4*)&W[(size_t)(k0 + kk) * Nw + n0 + nc * 4];
    Tf[kk][nc * 4 + 0] = a.x; Tf[kk][nc * 4 + 1] = a.y;
    Tf[kk][nc * 4 + 2] = a.z; Tf[kk][nc * 4 + 3] = a.w;
  }
  __syncthreads();
  const int n = t >> 2, cp = t & 3;
#pragma unroll
  for (int qq = 0; qq < 2; ++qq) {
    const int cc = cp * 2 + qq;
    union { unsigned short u[8]; uint4 v; } o;
#pragma unroll
    for (int e = 0; e < 8; ++e) o.u[e] = f2bf(Tf[cc * 8 + e][n]);
    const int ng = n0 + n;
    const int co = cc ^ (ng & 7);
    *(uint4*)&T[(size_t)ng * 256 + blockIdx.y * 64 + co * 8] = o.v;
  }
}

// ---------------------------------------------------------------------------
// bf16 MFMA GEMM + bias (unchanged from R2).
// ---------------------------------------------------------------------------
template <int BF16OUT>
__global__ __launch_bounds__(256) void mfma_gemm_kernel(
    const unsigned short* __restrict__ Abf,
    const unsigned short* __restrict__ B0, const unsigned short* __restrict__ B1,
    const unsigned short* __restrict__ B2,
    const float* __restrict__ bias0, const float* __restrict__ bias1,
    const float* __restrict__ bias2,
    void* __restrict__ C0v, void* __restrict__ C1v, void* __restrict__ C2v,
    int Nc) {
  const unsigned short* Bm = blockIdx.z == 0 ? B0 : blockIdx.z == 1 ? B1 : B2;
  const float* bias = blockIdx.z == 0 ? bias0 : blockIdx.z == 1 ? bias1 : bias2;
  void* Cv = blockIdx.z == 0 ? C0v : blockIdx.z == 1 ? C1v : C2v;

  __shared__ unsigned short lds[2 * 128 * 64];
  unsigned short* As = lds;
  unsigned short* Bs = lds + 128 * 64;

  const int t = threadIdx.x, l = t & 63, w = t >> 6;
  const int m0 = blockIdx.y * 128, n0 = blockIdx.x * 128;
  const int wm = w >> 1, wn = w & 1;

  const f32x4 zero = {0.f, 0.f, 0.f, 0.f};
  f32x4 acc[4][4];
#pragma unroll
  for (int fm = 0; fm < 4; ++fm)
#pragma unroll
    for (int fn = 0; fn < 4; ++fn) acc[fm][fn] = zero;

  for (int kb = 0; kb < 4; ++kb) {
#pragma unroll
    for (int r = 0; r < 4; ++r) {
      const int rr = r * 8 + (l >> 3), ch = l & 7;
      gload16(Abf + (size_t)(m0 + w * 32 + rr) * 256 + kb * 64 + ch * 8,
              As + w * 2048 + r * 512);
      gload16(Bm + (size_t)(n0 + w * 32 + rr) * 256 + kb * 64 + ch * 8,
              Bs + w * 2048 + r * 512);
    }
    __syncthreads();

#pragma unroll
    for (int s = 0; s < 2; ++s) {
      const int chab = (4 * s + (l >> 4)) ^ (l & 7);
      bf16x8 af[4], bfr[4];
#pragma unroll
      for (int fm = 0; fm < 4; ++fm) {
        const int row = wm * 64 + fm * 16 + (l & 15);
        af[fm] = *(const bf16x8*)&As[row * 64 + chab * 8];
      }
#pragma unroll
      for (int fn = 0; fn < 4; ++fn) {
        const int row = wn * 64 + fn * 16 + (l & 15);
        bfr[fn] = *(const bf16x8*)&Bs[row * 64 + chab * 8];
      }
#pragma unroll
      for (int fm = 0; fm < 4; ++fm)
#pragma unroll
        for (int fn = 0; fn < 4; ++fn)
          acc[fm][fn] = __builtin_amdgcn_mfma_f32_16x16x32_bf16(
              af[fm], bfr[fn], acc[fm][fn], 0, 0, 0);
    }
    __syncthreads();
  }

  float bv[4];
#pragma unroll
  for (int fn = 0; fn < 4; ++fn) bv[fn] = bias[n0 + wn * 64 + fn * 16 + (l & 15)];

  if (BF16OUT) {
    unsigned short* Cc = (unsigned short*)Cv;
#pragma unroll
    for (int fm = 0; fm < 4; ++fm) {
      const int colc = wn * 64 + (l & 15);
#pragma unroll
      for (int fn = 0; fn < 4; ++fn) {
        const int col = colc + fn * 16;
#pragma unroll
        for (int r = 0; r < 4; ++r) {
          const int row = wm * 64 + fm * 16 + (l >> 4) * 4 + r;
          const int pos = ((col >> 3) ^ (row & 15)) * 8 + (col & 7);
          lds[row * 128 + pos] = f2bf(acc[fm][fn][r] + bv[fn]);
        }
      }
    }
    __syncthreads();
#pragma unroll
    for (int r2 = 0; r2 < 8; ++r2) {
      const int idx = r2 * 256 + t;
      const int row = idx >> 4, ch = idx & 15;
      *(uint4*)&Cc[(size_t)(m0 + row) * Nc + n0 + ch * 8] =
          *(const uint4*)&lds[row * 128 + (ch ^ (row & 15)) * 8];
    }
  } else {
    float* Cc = (float*)Cv;
#pragma unroll
    for (int fm = 0; fm < 4; ++fm)
#pragma unroll
      for (int fn = 0; fn < 4; ++fn)
#pragma unroll
        for (int r = 0; r < 4; ++r) {
          const int row = wm * 64 + fm * 16 + (l >> 4) * 4 + r;
          const int col = wn * 64 + fn * 16 + (l & 15);
          Cc[(size_t)(m0 + row) * Nc + n0 + col] = acc[fm][fn][r] + bv[fn];
        }
  }
}

// ---------------------------------------------------------------------------
// bf16 -> fp8 e4m3 cast (hw packed cvt). idx covers 8 elements.
// ---------------------------------------------------------------------------
__global__ __launch_bounds__(256) void cast8_kernel(
    const unsigned short* __restrict__ in, unsigned char* __restrict__ out8, int n8) {
  const int idx = blockIdx.x * 256 + threadIdx.x;
  if (idx >= n8) return;
  const uint4 w = *(const uint4*)&in[(size_t)idx * 8];
  const float f0 = bfbits(w.x << 16), f1 = bfbits(w.x & 0xffff0000u);
  const float f2 = bfbits(w.y << 16), f3 = bfbits(w.y & 0xffff0000u);
  const float f4 = bfbits(w.z << 16), f5 = bfbits(w.z & 0xffff0000u);
  const float f6 = bfbits(w.w << 16), f7 = bfbits(w.w & 0xffff0000u);
  unsigned int lo = __builtin_amdgcn_cvt_pk_fp8_f32(f0, f1, 0, false);
  lo = __builtin_amdgcn_cvt_pk_fp8_f32(f2, f3, lo, true);
  unsigned int hi = __builtin_amdgcn_cvt_pk_fp8_f32(f4, f5, 0, false);
  hi = __builtin_amdgcn_cvt_pk_fp8_f32(f6, f7, hi, true);
  uint2 o; o.x = lo; o.y = hi;
  *(uint2*)&out8[(size_t)idx * 8] = o;
}

// ---------------------------------------------------------------------------
// Sparse attention (fp8 k/v, bf16 q) + head-mean + skip + LayerNorm + residual.
// One block (256 threads = 4 waves) per target node.
//   Score: lane -> (head=lane>>3, 32-elem slice), 2-deep pipelined k loads.
//   Agg:   lane -> (head-group=lane>>5, 8 channels), 2-deep pipelined v loads.
// ---------------------------------------------------------------------------
__global__ __launch_bounds__(256) void attn_ln_kernel(
    const unsigned short* __restrict__ q, const unsigned char* __restrict__ k8,
    const unsigned char* __restrict__ v8, const float* __restrict__ skip,
    const float* __restrict__ x, const int* __restrict__ deg,
    const int* __restrict__ nbr, const float* __restrict__ gamma,
    const float* __restrict__ beta, float* __restrict__ out) {
  const int i = blockIdx.x;
  const int t = threadIdx.x;
  const int lane = t & 63, wave = t >> 6;
  const int h = lane >> 3, sub = lane & 7;

  __shared__ int slist[CAP];
  __shared__ float sc[CAP * HH];
  __shared__ float wacc[4][2][DIMM];
  __shared__ float mred[HH], lred[HH];
  __shared__ float w1[4], w2[4];

  int d = deg[i];
  if (d > CAP) d = CAP;

  if (t < CAP) slist[t] = (t < d) ? nbr[i * CAP + t] : 0;

  // hoist q slice (32 elems of head h) into registers as f32
  float qf[32];
  {
    const uint4* qp = (const uint4*)&q[(size_t)i * HC + (h << 8) + (sub << 5)];
#pragma unroll
    for (int b = 0; b < 4; ++b) {
      const uint4 w = qp[b];
      qf[b * 8 + 0] = bfbits(w.x << 16); qf[b * 8 + 1] = bfbits(w.x & 0xffff0000u);
      qf[b * 8 + 2] = bfbits(w.y << 16); qf[b * 8 + 3] = bfbits(w.y & 0xffff0000u);
      qf[b * 8 + 4] = bfbits(w.z << 16); qf[b * 8 + 5] = bfbits(w.z & 0xffff0000u);
      qf[b * 8 + 6] = bfbits(w.w << 16); qf[b * 8 + 7] = bfbits(w.w & 0xffff0000u);
    }
  }
  __syncthreads();

  // ---- score phase: fp8 k rows, 2-deep software pipeline ----
  {
    const size_t hoff = (size_t)(h << 8) + (sub << 5);  // byte offset in row
    int n = wave;
    uint4 c0, c1;
    if (n < d) {
      const uint4* kp = (const uint4*)&k8[(size_t)slist[n] * HC + hoff];
      c0 = kp[0]; c1 = kp[1];
    }
    while (n < d) {
      const int nn = n + 4;
      uint4 p0, p1;
      if (nn < d) {
        const uint4* kp = (const uint4*)&k8[(size_t)slist[nn] * HC + hoff];
        p0 = kp[0]; p1 = kp[1];
      }
      float s = 0.f;
      const unsigned int cw[8] = {c0.x, c0.y, c0.z, c0.w, c1.x, c1.y, c1.z, c1.w};
#pragma unroll
      for (int b = 0; b < 8; ++b) {
        const f32x2 lo = __builtin_amdgcn_cvt_pk_f32_fp8(cw[b], false);
        const f32x2 hi = __builtin_amdgcn_cvt_pk_f32_fp8(cw[b], true);
        s = fmaf(qf[b * 4 + 0], lo[0], s);
        s = fmaf(qf[b * 4 + 1], lo[1], s);
        s = fmaf(qf[b * 4 + 2], hi[0], s);
        s = fmaf(qf[b * 4 + 3], hi[1], s);
      }
      s += __shfl_xor(s, 1);
      s += __shfl_xor(s, 2);
      s += __shfl_xor(s, 4);
      if (sub == 0) sc[n * HH + h] = s * 0.0625f;  // 1/sqrt(256)
      c0 = p0; c1 = p1;
      n = nn;
    }
  }
  __syncthreads();

  // ---- softmax stats: 64 threads, 8 per head, shfl-reduced ----
  if (t < 64) {
    const int h2 = t >> 3, s2 = t & 7;
    float m = -1e30f;
    for (int n2 = s2; n2 < d; n2 += 8) m = fmaxf(m, sc[n2 * HH + h2]);
    m = fmaxf(m, __shfl_xor(m, 1));
    m = fmaxf(m, __shfl_xor(m, 2));
    m = fmaxf(m, __shfl_xor(m, 4));
    float lsum = 0.f;
    for (int n2 = s2; n2 < d; n2 += 8) lsum += expf(sc[n2 * HH + h2] - m);
    lsum += __shfl_xor(lsum, 1);
    lsum += __shfl_xor(lsum, 2);
    lsum += __shfl_xor(lsum, 4);
    if (s2 == 0) { mred[h2] = m; lred[h2] = (lsum > 0.f) ? 1.f / lsum : 0.f; }
  }
  __syncthreads();

  for (int e = t; e < d * HH; e += 256) {
    const int hh = e & (HH - 1);
    sc[e] = expf(sc[e] - mred[hh]) * lred[hh];
  }
  __syncthreads();

  // ---- aggregate: fp8 v rows, 8 channels/lane, 2-deep pipeline ----
  float a[8] = {0.f, 0.f, 0.f, 0.f, 0.f, 0.f, 0.f, 0.f};
  const int g = lane >> 5, c8 = lane & 31;
  {
    const size_t voff = (size_t)(g * 4) * 256 + (size_t)c8 * 8;  // byte offset
    int n = wave;
    uint2 d0, d1, d2, d3;
    if (n < d) {
      const unsigned char* vr = &v8[(size_t)slist[n] * HC + voff];
      d0 = *(const uint2*)(vr + 0 * 256); d1 = *(const uint2*)(vr + 1 * 256);
      d2 = *(const uint2*)(vr + 2 * 256); d3 = *(const uint2*)(vr + 3 * 256);
    }
    while (n < d) {
      const int nn = n + 4;
      uint2 e0, e1, e2, e3;
      if (nn < d) {
        const unsigned char* vr = &v8[(size_t)slist[nn] * HC + voff];
        e0 = *(const uint2*)(vr + 0 * 256); e1 = *(const uint2*)(vr + 1 * 256);
        e2 = *(const uint2*)(vr + 2 * 256); e3 = *(const uint2*)(vr + 3 * 256);
      }
      const float p0 = sc[n * HH + g * 4 + 0];
      const float p1 = sc[n * HH + g * 4 + 1];
      const float p2 = sc[n * HH + g * 4 + 2];
      const float p3 = sc[n * HH + g * 4 + 3];
#define AGG_HEAD(w, p)                                                \
      {                                                               \
        const f32x2 u01 = __builtin_amdgcn_cvt_pk_f32_fp8((w).x, false); \
        const f32x2 u23 = __builtin_amdgcn_cvt_pk_f32_fp8((w).x, true);  \
        const f32x2 u45 = __builtin_amdgcn_cvt_pk_f32_fp8((w).y, false); \
        const f32x2 u67 = __builtin_amdgcn_cvt_pk_f32_fp8((w).y, true);  \
        a[0] = fmaf(p, u01[0], a[0]); a[1] = fmaf(p, u01[1], a[1]);   \
        a[2] = fmaf(p, u23[0], a[2]); a[3] = fmaf(p, u23[1], a[3]);   \
        a[4] = fmaf(p, u45[0], a[4]); a[5] = fmaf(p, u45[1], a[5]);   \
        a[6] = fmaf(p, u67[0], a[6]); a[7] = fmaf(p, u67[1], a[7]);   \
      }
      AGG_HEAD(d0, p0) AGG_HEAD(d1, p1) AGG_HEAD(d2, p2) AGG_HEAD(d3, p3)
#undef AGG_HEAD
      d0 = e0; d1 = e1; d2 = e2; d3 = e3;
      n = nn;
    }
  }
#pragma unroll
  for (int e = 0; e < 8; ++e) wacc[wave][g][c8 * 8 + e] = a[e];
  __syncthreads();

  // ---- head mean + skip + LayerNorm + residual (thread t = channel t) ----
  float accsum = 0.f;
#pragma unroll
  for (int w2 = 0; w2 < 4; ++w2) accsum += wacc[w2][0][t] + wacc[w2][1][t];
  const float oval = accsum * 0.125f + skip[(size_t)i * DIMM + t];

  float s1 = oval, s2 = oval * oval;
#pragma unroll
  for (int off = 32; off > 0; off >>= 1) {
    s1 += __shfl_xor(s1, off, 64);
    s2 += __shfl_xor(s2, off, 64);
  }
  if (lane == 0) { w1[wave] = s1; w2[wave] = s2; }
  __syncthreads();
  const float S1 = w1[0] + w1[1] + w1[2] + w1[3];
  const float S2 = w2[0] + w2[1] + w2[2] + w2[3];
  const float mu = S1 * (1.0f / 256.0f);
  const float var = S2 * (1.0f / 256.0f) - mu * mu;
  const float rst = rsqrtf(var + 1e-5f);

  out[(size_t)i * DIMM + t] =
      (oval - mu) * rst * gamma[t] + beta[t] + x[(size_t)i * DIMM + t];
}

// ---------------------------------------------------------------------------
extern "C" void kernel_launch(void* const* d_in, const int* in_sizes, int n_in,
                              void* d_out, int out_size, void* d_ws, size_t ws_size,
                              hipStream_t stream) {
  const float* x     = (const float*)d_in[0];
  const float* adj   = (const float*)d_in[1];
  const float* Wq    = (const float*)d_in[2];
  const float* bq    = (const float*)d_in[3];
  const float* Wk    = (const float*)d_in[4];
  const float* bk    = (const float*)d_in[5];
  const float* Wv    = (const float*)d_in[6];
  const float* bv    = (const float*)d_in[7];
  const float* Wskip = (const float*)d_in[8];
  const float* bskip = (const float*)d_in[9];
  const float* gamma = (const float*)d_in[10];
  const float* beta  = (const float*)d_in[11];
  float* out = (float*)d_out;

  // ws: xb | WqT | WkT | WvT | WsT | qb | kb | vb (bf16) | skip f32 | k8 v8 | deg | nbr
  char* ws = (char*)d_ws;
  unsigned short* xb  = (unsigned short*)ws;
  unsigned short* WqT = xb  + (size_t)NN * DIMM;
  unsigned short* WkT = WqT + (size_t)HC * DIMM;
  unsigned short* WvT = WkT + (size_t)HC * DIMM;
  unsigned short* WsT = WvT + (size_t)HC * DIMM;
  unsigned short* qb  = WsT + (size_t)DIMM * DIMM;
  unsigned short* kbf = qb  + (size_t)NN * HC;
  unsigned short* vbf = kbf + (size_t)NN * HC;
  float* skip = (float*)(vbf + (size_t)NN * HC);
  unsigned char* k8 = (unsigned char*)(skip + (size_t)NN * DIMM);
  unsigned char* v8 = k8 + (size_t)NN * HC;
  int* deg = (int*)(v8 + (size_t)NN * HC);
  int* nbr = deg + NN;

  hipMemsetAsync(deg, 0, NN * sizeof(int), stream);
  build_edges_kernel<<<2048, 256, 0, stream>>>((const float4*)adj, deg, nbr);
  sort_nbr_kernel<<<NN, 128, 0, stream>>>(deg, nbr);

  cast_x_kernel<<<NN * 32 / 256, 256, 0, stream>>>(x, xb);
  tcast_w_kernel<<<dim3(HC / 64, 4, 3), 256, 0, stream>>>(Wq, Wk, Wv, WqT, WkT, WvT, HC);
  tcast_w_kernel<<<dim3(DIMM / 64, 4, 1), 256, 0, stream>>>(Wskip, Wskip, Wskip,
                                                            WsT, WsT, WsT, DIMM);

  mfma_gemm_kernel<1><<<dim3(HC / 128, NN / 128, 3), 256, 0, stream>>>(
      xb, WqT, WkT, WvT, bq, bk, bv, qb, kbf, vbf, HC);
  mfma_gemm_kernel<0><<<dim3(DIMM / 128, NN / 128, 1), 256, 0, stream>>>(
      xb, WsT, WsT, WsT, bskip, bskip, bskip, skip, skip, skip, DIMM);

  // k,v (contiguous) -> fp8
  cast8_kernel<<<(2 * NN * HC / 8 + 255) / 256, 256, 0, stream>>>(
      kbf, k8, 2 * NN * HC / 8);

  attn_ln_kernel<<<NN, 256, 0, stream>>>(qb, k8, v8, skip, x, deg, nbr,
                                         gamma, beta, out);
}